// Round 3
// baseline (1200.858 us; speedup 1.0000x reference)
//
#include <hip/hip_runtime.h>

typedef unsigned long long ull;
typedef float nvec4 __attribute__((ext_vector_type(4)));  // native clang vector for nontemporal builtins

#define MMAX 128

// ---------------------------------------------------------------------------
// k_init: zero reduction scratch (bpi keys, counters, accumulators).
// Workspace is re-poisoned by the harness each iteration, so this must run.
// ---------------------------------------------------------------------------
__global__ void k_init(ull* __restrict__ bpi, int* __restrict__ cnt1,
                       float* __restrict__ cls_sum, float* __restrict__ reg_sum,
                       int* __restrict__ npos, int* __restrict__ cnt2,
                       int BM, int B) {
    int tid = threadIdx.x;
    for (int i = tid; i < BM; i += blockDim.x) bpi[i] = 0ull;
    if (tid < B) { cnt1[tid] = 0; cls_sum[tid] = 0.f; reg_sum[tid] = 0.f; npos[tid] = 0; }
    if (tid == 0) cnt2[0] = 0;
}

// ---------------------------------------------------------------------------
// k_iou: per-(b,anchor) row max/argmax over M gt boxes; per-(b,j) column
// argmax via packed (iou_bits<<32)|(~a) atomicMax. 4x thread coarsening.
// Tail: last block per b (completion counter) applies the forced-anchor
// replay (bto[a]=2, bti[a]=j, duplicate a resolved by max j == last write).
// ---------------------------------------------------------------------------
__global__ void k_iou(const float* __restrict__ anchors, const float* __restrict__ ann1,
                      float* __restrict__ bto, int* __restrict__ bti, ull* __restrict__ bpi,
                      int* __restrict__ cnt1, int A, int M) {
    __shared__ float s_box[MMAX][4];
    __shared__ float s_area[MMAX];
    __shared__ ull s_part[4][MMAX];
    const int b = blockIdx.y;
    const int tid = threadIdx.x;
    for (int i = tid; i < M; i += blockDim.x) {
        const float* g = ann1 + ((size_t)b * M + i) * 6;
        float x1 = g[0], y1 = g[1], x2 = g[2], y2 = g[3];
        s_box[i][0] = x1; s_box[i][1] = y1; s_box[i][2] = x2; s_box[i][3] = y2;
        s_area[i] = (x2 - x1) * (y2 - y1);
    }
    __syncthreads();

    const int base = blockIdx.x * (blockDim.x * 4);
    float ax1[4], ay1[4], ax2[4], ay2[4], aar[4];
    int aidx[4]; bool val[4];
#pragma unroll
    for (int u = 0; u < 4; ++u) {
        int a = base + u * blockDim.x + tid;
        aidx[u] = a; val[u] = (a < A);
        float4 av = make_float4(0.f, 0.f, 0.f, 0.f);
        if (val[u]) av = ((const float4*)anchors)[a];
        ax1[u] = av.x; ay1[u] = av.y; ax2[u] = av.z; ay2[u] = av.w;
        aar[u] = (av.z - av.x) * (av.w - av.y);
    }
    float best[4] = {-1.f, -1.f, -1.f, -1.f};
    int bestj[4] = {0, 0, 0, 0};
    const int lane = tid & 63, wid = tid >> 6;

    for (int j = 0; j < M; ++j) {
        float bx1 = s_box[j][0], by1 = s_box[j][1], bx2 = s_box[j][2], by2 = s_box[j][3];
        float bar = s_area[j];
        ull key = 0ull;
#pragma unroll
        for (int u = 0; u < 4; ++u) {
            float iw = fmaxf(fminf(ax2[u], bx2) - fmaxf(ax1[u], bx1), 0.f);
            float ih = fmaxf(fminf(ay2[u], by2) - fmaxf(ay1[u], by1), 0.f);
            float inter = iw * ih;
            float ua = fmaxf(aar[u] + bar - inter, 1e-8f);
            float iou = inter / ua;
            if (val[u]) {
                if (iou > best[u]) { best[u] = iou; bestj[u] = j; }  // strict > => first occurrence
                ull k2 = (((ull)__float_as_uint(iou)) << 32) | (ull)(0xFFFFFFFFu - (unsigned)aidx[u]);
                if (k2 > key) key = k2;  // ~a low word => ties pick min anchor index
            }
        }
#pragma unroll
        for (int off = 32; off > 0; off >>= 1) {
            ull o = __shfl_down(key, off);
            if (o > key) key = o;
        }
        if (lane == 0) s_part[wid][j] = key;
    }
#pragma unroll
    for (int u = 0; u < 4; ++u) {
        if (val[u]) {
            bto[(size_t)b * A + aidx[u]] = best[u];
            bti[(size_t)b * A + aidx[u]] = bestj[u];
        }
    }
    __syncthreads();
    for (int j = tid; j < M; j += blockDim.x) {
        ull key = s_part[0][j];
        if (s_part[1][j] > key) key = s_part[1][j];
        if (s_part[2][j] > key) key = s_part[2][j];
        if (s_part[3][j] > key) key = s_part[3][j];
        atomicMax(&bpi[(size_t)b * M + j], key);
    }

    // ---- completion-counter tail: last block of this b applies the force ----
    __threadfence();  // release: bto/bti stores + bpi atomics visible device-wide
    __shared__ int s_last;
    if (tid == 0) s_last = (atomicAdd(&cnt1[b], 1) == (int)gridDim.x - 1) ? 1 : 0;
    __syncthreads();
    if (s_last) {
        __shared__ unsigned s_fa[MMAX];
        if (tid < M) {
            ull key = atomicMax(&bpi[(size_t)b * M + tid], 0ull);  // coherent read
            s_fa[tid] = 0xFFFFFFFFu - (unsigned)(key & 0xFFFFFFFFull);
        }
        __syncthreads();
        if (tid < M) {
            unsigned a = s_fa[tid];
            bool win = true;  // last-write-wins: j loses if a higher j targets same anchor
            for (int j2 = tid + 1; j2 < M; ++j2)
                if (s_fa[j2] == a) { win = false; break; }
            if (win) {
                bto[(size_t)b * A + a] = 2.0f;
                bti[(size_t)b * A + a] = tid;
            }
        }
    }
}

// ---------------------------------------------------------------------------
// k_main: fused cls (focal) + reg (smooth-L1) + final normalize.
// Blocks [0, B*NBC) run the cls grid-stride float4 loop; blocks
// [B*NBC, B*(NBC+NBR)) run the per-anchor reg loop. Block-uniform split.
// Grid-wide completion counter: winner block normalizes and writes out.
// ---------------------------------------------------------------------------
template <int C4C>
__global__ void k_main(const float* __restrict__ cls, const float* __restrict__ regs,
                       const float* __restrict__ anchors, const float* __restrict__ ann1,
                       const float* __restrict__ ann2,
                       const float* __restrict__ bto, const int* __restrict__ bti,
                       float* __restrict__ cls_sum, float* __restrict__ reg_sum,
                       int* __restrict__ npos, int* __restrict__ cnt2,
                       float* __restrict__ out,
                       int A, int c4_rt, int M, int M2, int B, int NBC, int NBR) {
    const int c4 = (C4C > 0) ? C4C : c4_rt;
    const int bid = blockIdx.x;
    const int tid = threadIdx.x;
    __shared__ float s_a1[MMAX * 6];
    __shared__ float s_a2[MMAX * 6];
    __shared__ float s_red[4];
    __shared__ int s_redi[4];

    if (bid < B * NBC) {
        // ---------------- cls path ----------------
        const int b = bid / NBC;
        const int xb = bid - b * NBC;
        const int N4 = A * c4;
        const nvec4* cb = (const nvec4*)(cls + (size_t)b * A * (c4 * 4));
        const float* btob = bto + (size_t)b * A;
        const int* btib = bti + (size_t)b * A;
        const float* ann1b = ann1 + (size_t)b * M * 6;
        float lsum = 0.f;
        const int stride = NBC * blockDim.x;
        for (int i = xb * blockDim.x + tid; i < N4; i += stride) {
            int a = i / c4;
            int c0 = (i - a * c4) * 4;
            float v = btob[a];
            bool pos = (v >= 0.5f), neg = (v < 0.4f);
            if (pos || neg) {  // ignore band contributes 0 and skips the load
                nvec4 x = __builtin_nontemporal_load(&cb[i]);
                int label = -1;
                if (pos) label = (int)ann1b[btib[a] * 6 + 4];
                float xs[4] = {x[0], x[1], x[2], x[3]};
#pragma unroll
                for (int k = 0; k < 4; ++k) {
                    float p = fminf(fmaxf(xs[k], 1e-4f), 1.0f - 1e-4f);
                    if (pos && (c0 + k) == label) {
                        float q = 1.f - p;
                        lsum += 0.25f * q * q * (-__logf(p));
                    } else {
                        lsum += 0.75f * p * p * (-__logf(1.f - p));
                    }
                }
            }
        }
#pragma unroll
        for (int off = 32; off > 0; off >>= 1) lsum += __shfl_down(lsum, off);
        if ((tid & 63) == 0) s_red[tid >> 6] = lsum;
        __syncthreads();
        if (tid == 0)
            atomicAdd(&cls_sum[b], s_red[0] + s_red[1] + s_red[2] + s_red[3]);
    } else {
        // ---------------- reg path ----------------
        const int r = bid - B * NBC;
        const int b = r / NBR;
        const int xb = r - b * NBR;
        for (int i = tid; i < M * 6; i += blockDim.x) s_a1[i] = ann1[(size_t)b * M * 6 + i];
        for (int i = tid; i < M2 * 6; i += blockDim.x) s_a2[i] = ann2[(size_t)b * M2 * 6 + i];
        __syncthreads();

        const int a = xb * blockDim.x + tid;
        float sum = 0.f;
        int cnt = 0;
        if (a < A) {
            float v = bto[(size_t)b * A + a];
            if (v >= 0.5f) {
                cnt = 1;
                const int ji = bti[(size_t)b * A + a];
                const float* as = &s_a1[ji * 6];
                float4 av = ((const float4*)anchors)[a];
                float aw = av.z - av.x, ah = av.w - av.y;
                float acx = av.x + 0.5f * aw, acy = av.y + 0.5f * ah;
                float gw0 = as[2] - as[0], gh0 = as[3] - as[1];
                float gcx = as[0] + 0.5f * gw0, gcy = as[1] + 0.5f * gh0;
                float gw = fmaxf(gw0, 1.f), gh = fmaxf(gh0, 1.f);
                float t[8];
                t[0] = ((gcx - acx) / aw) / 0.1f;
                t[1] = ((gcy - acy) / ah) / 0.1f;
                t[2] = __logf(gw / aw) / 0.2f;
                t[3] = __logf(gh / ah) / 0.2f;
                int nterm = 4;
                float tid5 = as[5];
                int first = -1;
                for (int j2 = 0; j2 < M2; ++j2) {
                    if (s_a2[j2 * 6 + 5] == tid5) { first = j2; break; }  // first match
                }
                if (first >= 0) {
                    const float* ns = &s_a2[first * 6];
                    float nw0 = ns[2] - ns[0], nh0 = ns[3] - ns[1];
                    float ncx = ns[0] + 0.5f * nw0, ncy = ns[1] + 0.5f * nh0;
                    float nw = fmaxf(nw0, 1.f), nh = fmaxf(nh0, 1.f);
                    t[4] = ((ncx - acx) / aw) / 0.1f;
                    t[5] = ((ncy - acy) / ah) / 0.1f;
                    t[6] = __logf(nw / aw) / 0.2f;
                    t[7] = __logf(nh / ah) / 0.2f;
                    nterm = 8;
                }
                const float* rg = regs + ((size_t)b * A + a) * 8;
                for (int k = 0; k < nterm; ++k) {
                    float d = fabsf(t[k] - __builtin_nontemporal_load(&rg[k]));
                    sum += (d <= (1.0f / 9.0f)) ? (4.5f * d * d) : (d - (0.5f / 9.0f));
                }
            }
        }
#pragma unroll
        for (int off = 32; off > 0; off >>= 1) {
            sum += __shfl_down(sum, off);
            cnt += __shfl_down(cnt, off);
        }
        if ((tid & 63) == 0) { s_red[tid >> 6] = sum; s_redi[tid >> 6] = cnt; }
        __syncthreads();
        if (tid == 0) {
            atomicAdd(&reg_sum[b], s_red[0] + s_red[1] + s_red[2] + s_red[3]);
            atomicAdd(&npos[b], s_redi[0] + s_redi[1] + s_redi[2] + s_redi[3]);
        }
    }

    // ---- completion-counter tail: winner normalizes + writes out ----
    __threadfence();  // release: this block's atomics visible device-wide
    __shared__ int s_win;
    if (tid == 0) s_win = (atomicAdd(cnt2, 1) == (int)gridDim.x - 1) ? 1 : 0;
    __syncthreads();
    if (s_win && tid == 0) {
        float c = 0.f, rr = 0.f;
        for (int b2 = 0; b2 < B; ++b2) {
            float cs = atomicAdd(&cls_sum[b2], 0.f);   // coherent reads
            float rs = atomicAdd(&reg_sum[b2], 0.f);
            int np = atomicAdd(&npos[b2], 0);
            float npf = (float)np;
            c += cs / fmaxf(npf, 1.f);
            rr += rs / fmaxf(npf * 8.f, 1.f);
        }
        out[0] = c / (float)B;
        out[1] = rr / (float)B;
    }
}

extern "C" void kernel_launch(void* const* d_in, const int* in_sizes, int n_in,
                              void* d_out, int out_size, void* d_ws, size_t ws_size,
                              hipStream_t stream) {
    const float* cls = (const float*)d_in[0];
    const float* regs = (const float*)d_in[1];
    const float* anchors = (const float*)d_in[2];
    const float* ann1 = (const float*)d_in[3];
    const float* ann2 = (const float*)d_in[4];
    float* out = (float*)d_out;

    const int A = in_sizes[2] / 4;           // anchors [1,A,4]
    const int B = in_sizes[1] / (A * 8);     // regressions [B,A,8]
    const int C = in_sizes[0] / (B * A);     // classifications [B,A,C]
    const int M = in_sizes[3] / (B * 6);     // annotations1 [B,M,6]
    const int M2 = in_sizes[4] / (B * 6);    // annotations2 [B,M2,6]

    char* ws = (char*)d_ws;
    size_t off = 0;
    ull* bpi = (ull*)(ws + off);      off += (size_t)B * M * sizeof(ull);   off = (off + 255) & ~(size_t)255;
    int* cnt1 = (int*)(ws + off);     off += (size_t)B * sizeof(int);       off = (off + 255) & ~(size_t)255;
    float* cls_sum = (float*)(ws + off); off += (size_t)B * sizeof(float);  off = (off + 255) & ~(size_t)255;
    float* reg_sum = (float*)(ws + off); off += (size_t)B * sizeof(float);  off = (off + 255) & ~(size_t)255;
    int* npos = (int*)(ws + off);     off += (size_t)B * sizeof(int);       off = (off + 255) & ~(size_t)255;
    int* cnt2 = (int*)(ws + off);     off += 256;
    float* bto = (float*)(ws + off);  off += (size_t)B * A * sizeof(float); off = (off + 255) & ~(size_t)255;
    int* bti = (int*)(ws + off);      off += (size_t)B * A * sizeof(int);

    k_init<<<dim3(1), dim3(512), 0, stream>>>(bpi, cnt1, cls_sum, reg_sum, npos, cnt2, B * M, B);

    dim3 g1((A + 1023) / 1024, B);
    k_iou<<<g1, dim3(256), 0, stream>>>(anchors, ann1, bto, bti, bpi, cnt1, A, M);

    const int NBC = 512;                 // cls blocks per b (grid-stride)
    const int NBR = (A + 255) / 256;     // reg blocks per b (one anchor/thread)
    dim3 g2(B * (NBC + NBR));
    if (C % 4 == 0 && C / 4 == 20)
        k_main<20><<<g2, dim3(256), 0, stream>>>(cls, regs, anchors, ann1, ann2, bto, bti,
                                                 cls_sum, reg_sum, npos, cnt2, out,
                                                 A, C / 4, M, M2, B, NBC, NBR);
    else
        k_main<0><<<g2, dim3(256), 0, stream>>>(cls, regs, anchors, ann1, ann2, bto, bti,
                                                cls_sum, reg_sum, npos, cnt2, out,
                                                A, C / 4, M, M2, B, NBC, NBR);
}

// Round 5
// 482.827 us; speedup vs baseline: 2.4871x; 2.4871x over previous
//
#include <hip/hip_runtime.h>

typedef unsigned long long ull;

#define MMAX 128
#define BMAX 16
#define TILE 128

// ---------------------------------------------------------------------------
// k_init: zero the small reduction scratch (bpi keys, npos, cls/reg sums)
// ---------------------------------------------------------------------------
__global__ void k_init(ull* __restrict__ bpi, int* __restrict__ npos,
                       float* __restrict__ cls_sum, float* __restrict__ reg_sum,
                       int BM, int B) {
    int i = blockIdx.x * blockDim.x + threadIdx.x;
    if (i < BM) bpi[i] = 0ull;
    if (i < B) { npos[i] = 0; cls_sum[i] = 0.f; reg_sum[i] = 0.f; }
}

// ---------------------------------------------------------------------------
// k_iou: per-(b,anchor) row max/argmax over M gt boxes; per-(b,j) column
// argmax over anchors via packed (iou_bits<<32)|(~a) atomicMax.
// 4x thread coarsening to amortize the wave reduction. (round-2 verified)
// ---------------------------------------------------------------------------
__global__ void k_iou(const float* __restrict__ anchors, const float* __restrict__ ann1,
                      float* __restrict__ bto, int* __restrict__ bti, ull* __restrict__ bpi,
                      int A, int M) {
    __shared__ float s_box[MMAX][4];
    __shared__ float s_area[MMAX];
    __shared__ ull s_part[4][MMAX];
    const int b = blockIdx.y;
    const int tid = threadIdx.x;
    for (int i = tid; i < M; i += blockDim.x) {
        const float* g = ann1 + ((size_t)b * M + i) * 6;
        float x1 = g[0], y1 = g[1], x2 = g[2], y2 = g[3];
        s_box[i][0] = x1; s_box[i][1] = y1; s_box[i][2] = x2; s_box[i][3] = y2;
        s_area[i] = (x2 - x1) * (y2 - y1);
    }
    __syncthreads();

    const int base = blockIdx.x * (blockDim.x * 4);
    float ax1[4], ay1[4], ax2[4], ay2[4], aar[4];
    int aidx[4]; bool val[4];
#pragma unroll
    for (int u = 0; u < 4; ++u) {
        int a = base + u * blockDim.x + tid;
        aidx[u] = a; val[u] = (a < A);
        float4 av = make_float4(0.f, 0.f, 0.f, 0.f);
        if (val[u]) av = ((const float4*)anchors)[a];
        ax1[u] = av.x; ay1[u] = av.y; ax2[u] = av.z; ay2[u] = av.w;
        aar[u] = (av.z - av.x) * (av.w - av.y);
    }
    float best[4] = {-1.f, -1.f, -1.f, -1.f};
    int bestj[4] = {0, 0, 0, 0};
    const int lane = tid & 63, wid = tid >> 6;

    for (int j = 0; j < M; ++j) {
        float bx1 = s_box[j][0], by1 = s_box[j][1], bx2 = s_box[j][2], by2 = s_box[j][3];
        float bar = s_area[j];
        ull key = 0ull;
#pragma unroll
        for (int u = 0; u < 4; ++u) {
            float iw = fmaxf(fminf(ax2[u], bx2) - fmaxf(ax1[u], bx1), 0.f);
            float ih = fmaxf(fminf(ay2[u], by2) - fmaxf(ay1[u], by1), 0.f);
            float inter = iw * ih;
            float ua = fmaxf(aar[u] + bar - inter, 1e-8f);
            float iou = inter / ua;
            if (val[u]) {
                if (iou > best[u]) { best[u] = iou; bestj[u] = j; }  // strict > => first occurrence
                ull k2 = (((ull)__float_as_uint(iou)) << 32) | (ull)(0xFFFFFFFFu - (unsigned)aidx[u]);
                if (k2 > key) key = k2;  // ~a low word => ties pick min anchor index
            }
        }
#pragma unroll
        for (int off = 32; off > 0; off >>= 1) {
            ull o = __shfl_down(key, off);
            if (o > key) key = o;
        }
        if (lane == 0) s_part[wid][j] = key;
    }
#pragma unroll
    for (int u = 0; u < 4; ++u) {
        if (val[u]) {
            bto[(size_t)b * A + aidx[u]] = best[u];
            bti[(size_t)b * A + aidx[u]] = bestj[u];
        }
    }
    __syncthreads();
    for (int j = tid; j < M; j += blockDim.x) {
        ull key = s_part[0][j];
        if (s_part[1][j] > key) key = s_part[1][j];
        if (s_part[2][j] > key) key = s_part[2][j];
        if (s_part[3][j] > key) key = s_part[3][j];
        atomicMax(&bpi[(size_t)b * M + j], key);
    }
}

// ---------------------------------------------------------------------------
// k_force: parallel replay of  bto[bpi[j]]=2.0 ; bti[bpi[j]]=j.
// One thread per (j,b); duplicate anchors resolved by max-j (== last write
// of the ascending-j sequential loop). blockDim = (M, B).
// ---------------------------------------------------------------------------
__global__ void k_force(const ull* __restrict__ bpi, float* __restrict__ bto,
                        int* __restrict__ bti, int A, int M, int B) {
    __shared__ unsigned s_fa[BMAX][MMAX];
    const int j = threadIdx.x;   // < M
    const int b = threadIdx.y;   // < B
    ull key = bpi[(size_t)b * M + j];
    unsigned a = 0xFFFFFFFFu - (unsigned)(key & 0xFFFFFFFFull);
    s_fa[b][j] = a;
    __syncthreads();
    bool win = true;  // lose if a higher j targets the same anchor
    for (int j2 = j + 1; j2 < M; ++j2)
        if (s_fa[b][j2] == a) { win = false; break; }
    if (win) {
        bto[(size_t)b * A + a] = 2.0f;
        bti[(size_t)b * A + a] = j;
    }
}

// ---------------------------------------------------------------------------
// k_cls: focal classification loss, anchor-tiled.
// Phase 1: per-anchor code (-2 ignore / -1 neg / label if pos) -> LDS.
// Phase 2: 128 anchors x c4 float4, perfectly coalesced, branch on LDS code.
// ---------------------------------------------------------------------------
template <int C4C>
__global__ void k_cls(const float* __restrict__ cls, const float* __restrict__ ann1,
                      const float* __restrict__ bto, const int* __restrict__ bti,
                      float* __restrict__ cls_sum, int A, int c4_rt, int M) {
    const int c4 = (C4C > 0) ? C4C : c4_rt;
    const int b = blockIdx.y;
    const int tid = threadIdx.x;
    const int base_a = blockIdx.x * TILE;
    __shared__ int s_code[TILE];
    __shared__ float s_red[4];

    if (tid < TILE) {
        int a = base_a + tid;
        int code = -2;
        if (a < A) {
            float v = bto[(size_t)b * A + a];
            if (v >= 0.5f)
                code = (int)ann1[((size_t)b * M + bti[(size_t)b * A + a]) * 6 + 4];
            else if (v < 0.4f)
                code = -1;
        }
        s_code[tid] = code;
    }
    __syncthreads();

    const float4* cb = (const float4*)(cls + (size_t)b * A * (c4 * 4));
    float lsum = 0.f;
    const int nf4 = TILE * c4;
    for (int i = tid; i < nf4; i += 256) {
        int al = i / c4;            // const divide -> magic mul
        int f = i - al * c4;
        int a = base_a + al;
        if (a < A) {
            int code = s_code[al];
            if (code != -2) {       // ignore band contributes 0 and skips the load
                float4 x = cb[(size_t)a * c4 + f];
                int c0 = f * 4;
                float xs[4] = {x.x, x.y, x.z, x.w};
#pragma unroll
                for (int k = 0; k < 4; ++k) {
                    float p = fminf(fmaxf(xs[k], 1e-4f), 1.0f - 1e-4f);
                    if (code == c0 + k) {        // pos anchor, target class
                        float q = 1.f - p;
                        lsum += 0.25f * q * q * (-__logf(p));
                    } else {                     // neg anchor or non-target class
                        lsum += 0.75f * p * p * (-__logf(1.f - p));
                    }
                }
            }
        }
    }
#pragma unroll
    for (int off = 32; off > 0; off >>= 1) lsum += __shfl_down(lsum, off);
    if ((tid & 63) == 0) s_red[tid >> 6] = lsum;
    __syncthreads();
    if (tid == 0)
        atomicAdd(&cls_sum[b], s_red[0] + s_red[1] + s_red[2] + s_red[3]);
}

// ---------------------------------------------------------------------------
// k_reg: smooth-L1 regression loss over positive anchors + npos count.
// (round-2 verified, nt hints removed)
// ---------------------------------------------------------------------------
__global__ void k_reg(const float* __restrict__ anchors, const float* __restrict__ ann1,
                      const float* __restrict__ ann2, const float* __restrict__ regs,
                      const float* __restrict__ bto, const int* __restrict__ bti,
                      float* __restrict__ reg_sum, int* __restrict__ npos,
                      int A, int M, int M2) {
    __shared__ float s_a1[MMAX * 6];
    __shared__ float s_a2[MMAX * 6];
    const int b = blockIdx.y;
    const int tid = threadIdx.x;
    for (int i = tid; i < M * 6; i += blockDim.x) s_a1[i] = ann1[(size_t)b * M * 6 + i];
    for (int i = tid; i < M2 * 6; i += blockDim.x) s_a2[i] = ann2[(size_t)b * M2 * 6 + i];
    __syncthreads();

    const int a = blockIdx.x * blockDim.x + tid;
    float sum = 0.f;
    int cnt = 0;
    if (a < A) {
        float v = bto[(size_t)b * A + a];
        if (v >= 0.5f) {
            cnt = 1;
            const int ji = bti[(size_t)b * A + a];
            const float* as = &s_a1[ji * 6];
            float4 av = ((const float4*)anchors)[a];
            float aw = av.z - av.x, ah = av.w - av.y;
            float acx = av.x + 0.5f * aw, acy = av.y + 0.5f * ah;
            float gw0 = as[2] - as[0], gh0 = as[3] - as[1];
            float gcx = as[0] + 0.5f * gw0, gcy = as[1] + 0.5f * gh0;
            float gw = fmaxf(gw0, 1.f), gh = fmaxf(gh0, 1.f);
            float t[8];
            t[0] = ((gcx - acx) / aw) / 0.1f;
            t[1] = ((gcy - acy) / ah) / 0.1f;
            t[2] = __logf(gw / aw) / 0.2f;
            t[3] = __logf(gh / ah) / 0.2f;
            int nterm = 4;
            float tid5 = as[5];
            int first = -1;
            for (int j2 = 0; j2 < M2; ++j2) {
                if (s_a2[j2 * 6 + 5] == tid5) { first = j2; break; }  // first match
            }
            if (first >= 0) {
                const float* ns = &s_a2[first * 6];
                float nw0 = ns[2] - ns[0], nh0 = ns[3] - ns[1];
                float ncx = ns[0] + 0.5f * nw0, ncy = ns[1] + 0.5f * nh0;
                float nw = fmaxf(nw0, 1.f), nh = fmaxf(nh0, 1.f);
                t[4] = ((ncx - acx) / aw) / 0.1f;
                t[5] = ((ncy - acy) / ah) / 0.1f;
                t[6] = __logf(nw / aw) / 0.2f;
                t[7] = __logf(nh / ah) / 0.2f;
                nterm = 8;
            }
            const float* rg = regs + ((size_t)b * A + a) * 8;
            for (int k = 0; k < nterm; ++k) {
                float d = fabsf(t[k] - rg[k]);
                sum += (d <= (1.0f / 9.0f)) ? (4.5f * d * d) : (d - (0.5f / 9.0f));
            }
        }
    }
#pragma unroll
    for (int off = 32; off > 0; off >>= 1) {
        sum += __shfl_down(sum, off);
        cnt += __shfl_down(cnt, off);
    }
    __shared__ float s_rs[4];
    __shared__ int s_rc[4];
    if ((tid & 63) == 0) { s_rs[tid >> 6] = sum; s_rc[tid >> 6] = cnt; }
    __syncthreads();
    if (tid == 0) {
        atomicAdd(&reg_sum[b], s_rs[0] + s_rs[1] + s_rs[2] + s_rs[3]);
        atomicAdd(&npos[b], s_rc[0] + s_rc[1] + s_rc[2] + s_rc[3]);
    }
}

// ---------------------------------------------------------------------------
// k_final: per-sample normalization + batch mean -> out[0], out[1]
// ---------------------------------------------------------------------------
__global__ void k_final(const float* __restrict__ cls_sum, const float* __restrict__ reg_sum,
                        const int* __restrict__ npos, float* __restrict__ out, int B) {
    if (blockIdx.x == 0 && threadIdx.x == 0) {
        float c = 0.f, r = 0.f;
        for (int b = 0; b < B; ++b) {
            float np_ = (float)npos[b];
            c += cls_sum[b] / fmaxf(np_, 1.f);
            r += reg_sum[b] / fmaxf(np_ * 8.f, 1.f);
        }
        out[0] = c / (float)B;
        out[1] = r / (float)B;
    }
}

extern "C" void kernel_launch(void* const* d_in, const int* in_sizes, int n_in,
                              void* d_out, int out_size, void* d_ws, size_t ws_size,
                              hipStream_t stream) {
    const float* cls = (const float*)d_in[0];
    const float* regs = (const float*)d_in[1];
    const float* anchors = (const float*)d_in[2];
    const float* ann1 = (const float*)d_in[3];
    const float* ann2 = (const float*)d_in[4];
    float* out = (float*)d_out;

    const int A = in_sizes[2] / 4;           // anchors [1,A,4]
    const int B = in_sizes[1] / (A * 8);     // regressions [B,A,8]
    const int C = in_sizes[0] / (B * A);     // classifications [B,A,C]
    const int M = in_sizes[3] / (B * 6);     // annotations1 [B,M,6]
    const int M2 = in_sizes[4] / (B * 6);    // annotations2 [B,M2,6]

    char* ws = (char*)d_ws;
    size_t off = 0;
    ull* bpi = (ull*)(ws + off);      off += (size_t)B * M * sizeof(ull);   off = (off + 255) & ~(size_t)255;
    int* npos = (int*)(ws + off);     off += (size_t)B * sizeof(int);       off = (off + 255) & ~(size_t)255;
    float* cls_sum = (float*)(ws + off); off += (size_t)B * sizeof(float);  off = (off + 255) & ~(size_t)255;
    float* reg_sum = (float*)(ws + off); off += (size_t)B * sizeof(float);  off = (off + 255) & ~(size_t)255;
    float* bto = (float*)(ws + off);  off += (size_t)B * A * sizeof(float); off = (off + 255) & ~(size_t)255;
    int* bti = (int*)(ws + off);      off += (size_t)B * A * sizeof(int);

    int initN = (B * M > B) ? B * M : B;
    k_init<<<dim3((initN + 255) / 256), dim3(256), 0, stream>>>(bpi, npos, cls_sum, reg_sum, B * M, B);

    dim3 g1((A + 1023) / 1024, B);
    k_iou<<<g1, dim3(256), 0, stream>>>(anchors, ann1, bto, bti, bpi, A, M);

    k_force<<<dim3(1), dim3(M, B), 0, stream>>>(bpi, bto, bti, A, M, B);

    dim3 g3((A + TILE - 1) / TILE, B);
    if (C % 4 == 0 && C / 4 == 20)
        k_cls<20><<<g3, dim3(256), 0, stream>>>(cls, ann1, bto, bti, cls_sum, A, C / 4, M);
    else
        k_cls<0><<<g3, dim3(256), 0, stream>>>(cls, ann1, bto, bti, cls_sum, A, C / 4, M);

    dim3 g4((A + 255) / 256, B);
    k_reg<<<g4, dim3(256), 0, stream>>>(anchors, ann1, ann2, regs, bto, bti, reg_sum, npos, A, M, M2);

    k_final<<<1, 1, 0, stream>>>(cls_sum, reg_sum, npos, out, B);
}

// Round 6
// 435.198 us; speedup vs baseline: 2.7593x; 1.1094x over previous
//
#include <hip/hip_runtime.h>

typedef unsigned long long ull;

#define MMAX 128
#define BMAX 16
#define CTILE 256

// ---------------------------------------------------------------------------
// k_init: zero the small reduction scratch (bpi keys, npos, cls/reg sums)
// ---------------------------------------------------------------------------
__global__ void k_init(ull* __restrict__ bpi, int* __restrict__ npos,
                       float* __restrict__ cls_sum, float* __restrict__ reg_sum,
                       int BM, int B) {
    int i = blockIdx.x * blockDim.x + threadIdx.x;
    if (i < BM) bpi[i] = 0ull;
    if (i < B) { npos[i] = 0; cls_sum[i] = 0.f; reg_sum[i] = 0.f; }
}

// ---------------------------------------------------------------------------
// k_iou: per-(b,anchor) row max/argmax over M gt boxes; per-(b,j) column
// argmax over anchors via packed (iou_bits<<32)|(~a) atomicMax.
// 4x thread coarsening to amortize the wave reduction. (round-2/5 verified)
// ---------------------------------------------------------------------------
__global__ void k_iou(const float* __restrict__ anchors, const float* __restrict__ ann1,
                      float* __restrict__ bto, int* __restrict__ bti, ull* __restrict__ bpi,
                      int A, int M) {
    __shared__ float s_box[MMAX][4];
    __shared__ float s_area[MMAX];
    __shared__ ull s_part[4][MMAX];
    const int b = blockIdx.y;
    const int tid = threadIdx.x;
    for (int i = tid; i < M; i += blockDim.x) {
        const float* g = ann1 + ((size_t)b * M + i) * 6;
        float x1 = g[0], y1 = g[1], x2 = g[2], y2 = g[3];
        s_box[i][0] = x1; s_box[i][1] = y1; s_box[i][2] = x2; s_box[i][3] = y2;
        s_area[i] = (x2 - x1) * (y2 - y1);
    }
    __syncthreads();

    const int base = blockIdx.x * (blockDim.x * 4);
    float ax1[4], ay1[4], ax2[4], ay2[4], aar[4];
    int aidx[4]; bool val[4];
#pragma unroll
    for (int u = 0; u < 4; ++u) {
        int a = base + u * blockDim.x + tid;
        aidx[u] = a; val[u] = (a < A);
        float4 av = make_float4(0.f, 0.f, 0.f, 0.f);
        if (val[u]) av = ((const float4*)anchors)[a];
        ax1[u] = av.x; ay1[u] = av.y; ax2[u] = av.z; ay2[u] = av.w;
        aar[u] = (av.z - av.x) * (av.w - av.y);
    }
    float best[4] = {-1.f, -1.f, -1.f, -1.f};
    int bestj[4] = {0, 0, 0, 0};
    const int lane = tid & 63, wid = tid >> 6;

    for (int j = 0; j < M; ++j) {
        float bx1 = s_box[j][0], by1 = s_box[j][1], bx2 = s_box[j][2], by2 = s_box[j][3];
        float bar = s_area[j];
        ull key = 0ull;
#pragma unroll
        for (int u = 0; u < 4; ++u) {
            float iw = fmaxf(fminf(ax2[u], bx2) - fmaxf(ax1[u], bx1), 0.f);
            float ih = fmaxf(fminf(ay2[u], by2) - fmaxf(ay1[u], by1), 0.f);
            float inter = iw * ih;
            float ua = fmaxf(aar[u] + bar - inter, 1e-8f);
            float iou = inter / ua;
            if (val[u]) {
                if (iou > best[u]) { best[u] = iou; bestj[u] = j; }  // strict > => first occurrence
                ull k2 = (((ull)__float_as_uint(iou)) << 32) | (ull)(0xFFFFFFFFu - (unsigned)aidx[u]);
                if (k2 > key) key = k2;  // ~a low word => ties pick min anchor index
            }
        }
#pragma unroll
        for (int off = 32; off > 0; off >>= 1) {
            ull o = __shfl_down(key, off);
            if (o > key) key = o;
        }
        if (lane == 0) s_part[wid][j] = key;
    }
#pragma unroll
    for (int u = 0; u < 4; ++u) {
        if (val[u]) {
            bto[(size_t)b * A + aidx[u]] = best[u];
            bti[(size_t)b * A + aidx[u]] = bestj[u];
        }
    }
    __syncthreads();
    for (int j = tid; j < M; j += blockDim.x) {
        ull key = s_part[0][j];
        if (s_part[1][j] > key) key = s_part[1][j];
        if (s_part[2][j] > key) key = s_part[2][j];
        if (s_part[3][j] > key) key = s_part[3][j];
        atomicMax(&bpi[(size_t)b * M + j], key);
    }
}

// ---------------------------------------------------------------------------
// k_force: parallel replay of  bto[bpi[j]]=2.0 ; bti[bpi[j]]=j.
// One thread per (j,b); duplicate anchors resolved by max-j (== last write
// of the ascending-j sequential loop). blockDim = (M, B). (round-5 verified)
// ---------------------------------------------------------------------------
__global__ void k_force(const ull* __restrict__ bpi, float* __restrict__ bto,
                        int* __restrict__ bti, int A, int M, int B) {
    __shared__ unsigned s_fa[BMAX][MMAX];
    const int j = threadIdx.x;   // < M
    const int b = threadIdx.y;   // < B
    ull key = bpi[(size_t)b * M + j];
    unsigned a = 0xFFFFFFFFu - (unsigned)(key & 0xFFFFFFFFull);
    s_fa[b][j] = a;
    __syncthreads();
    bool win = true;  // lose if a higher j targets the same anchor
    for (int j2 = j + 1; j2 < M; ++j2)
        if (s_fa[b][j2] == a) { win = false; break; }
    if (win) {
        bto[(size_t)b * A + a] = 2.0f;
        bti[(size_t)b * A + a] = j;
    }
}

// ---------------------------------------------------------------------------
// k_cr: merged cls (focal) + reg (smooth-L1) in ONE dispatch.
// Both paths only READ bto/bti (post-force) and write disjoint accumulators,
// so no fence is needed. Blocks [0, B*NBC): cls tiles (CTILE anchors each);
// blocks [B*NBC, B*(NBC+NBR)): reg blocks (256 anchors each).
// cls path = round-5-verified logic widened to CTILE=256 (all threads in
// phase 1, 20 coalesced float4 iters in phase 2).
// ---------------------------------------------------------------------------
template <int C4C>
__global__ void k_cr(const float* __restrict__ cls, const float* __restrict__ regs,
                     const float* __restrict__ anchors, const float* __restrict__ ann1,
                     const float* __restrict__ ann2,
                     const float* __restrict__ bto, const int* __restrict__ bti,
                     float* __restrict__ cls_sum, float* __restrict__ reg_sum,
                     int* __restrict__ npos,
                     int A, int c4_rt, int M, int M2, int B, int NBC, int NBR) {
    const int c4 = (C4C > 0) ? C4C : c4_rt;
    const int bid = blockIdx.x;
    const int tid = threadIdx.x;
    __shared__ float s_red[4];
    __shared__ int s_redi[4];

    if (bid < B * NBC) {
        // ---------------- cls path ----------------
        const int b = bid / NBC;
        const int base_a = (bid - b * NBC) * CTILE;
        __shared__ int s_code[CTILE];

        {
            int a = base_a + tid;
            int code = -2;
            if (a < A) {
                float v = bto[(size_t)b * A + a];
                if (v >= 0.5f)
                    code = (int)ann1[((size_t)b * M + bti[(size_t)b * A + a]) * 6 + 4];
                else if (v < 0.4f)
                    code = -1;
            }
            s_code[tid] = code;
        }
        __syncthreads();

        const float4* cb = (const float4*)(cls + (size_t)b * A * (c4 * 4));
        float lsum = 0.f;
        const int nf4 = CTILE * c4;
        for (int i = tid; i < nf4; i += 256) {
            int al = i / c4;            // const divide -> magic mul
            int f = i - al * c4;
            int a = base_a + al;
            if (a < A) {
                int code = s_code[al];
                if (code != -2) {       // ignore band contributes 0 and skips the load
                    float4 x = cb[(size_t)a * c4 + f];
                    int c0 = f * 4;
                    float xs[4] = {x.x, x.y, x.z, x.w};
#pragma unroll
                    for (int k = 0; k < 4; ++k) {
                        float p = fminf(fmaxf(xs[k], 1e-4f), 1.0f - 1e-4f);
                        if (code == c0 + k) {        // pos anchor, target class
                            float q = 1.f - p;
                            lsum += 0.25f * q * q * (-__logf(p));
                        } else {                     // neg anchor or non-target class
                            lsum += 0.75f * p * p * (-__logf(1.f - p));
                        }
                    }
                }
            }
        }
#pragma unroll
        for (int off = 32; off > 0; off >>= 1) lsum += __shfl_down(lsum, off);
        if ((tid & 63) == 0) s_red[tid >> 6] = lsum;
        __syncthreads();
        if (tid == 0)
            atomicAdd(&cls_sum[b], s_red[0] + s_red[1] + s_red[2] + s_red[3]);
    } else {
        // ---------------- reg path ----------------
        const int r = bid - B * NBC;
        const int b = r / NBR;
        const int xb = r - b * NBR;
        __shared__ float s_a1[MMAX * 6];
        __shared__ float s_a2[MMAX * 6];
        for (int i = tid; i < M * 6; i += blockDim.x) s_a1[i] = ann1[(size_t)b * M * 6 + i];
        for (int i = tid; i < M2 * 6; i += blockDim.x) s_a2[i] = ann2[(size_t)b * M2 * 6 + i];
        __syncthreads();

        const int a = xb * 256 + tid;
        float sum = 0.f;
        int cnt = 0;
        if (a < A) {
            float v = bto[(size_t)b * A + a];
            if (v >= 0.5f) {
                cnt = 1;
                const int ji = bti[(size_t)b * A + a];
                const float* as = &s_a1[ji * 6];
                float4 av = ((const float4*)anchors)[a];
                float aw = av.z - av.x, ah = av.w - av.y;
                float acx = av.x + 0.5f * aw, acy = av.y + 0.5f * ah;
                float gw0 = as[2] - as[0], gh0 = as[3] - as[1];
                float gcx = as[0] + 0.5f * gw0, gcy = as[1] + 0.5f * gh0;
                float gw = fmaxf(gw0, 1.f), gh = fmaxf(gh0, 1.f);
                float t[8];
                t[0] = ((gcx - acx) / aw) / 0.1f;
                t[1] = ((gcy - acy) / ah) / 0.1f;
                t[2] = __logf(gw / aw) / 0.2f;
                t[3] = __logf(gh / ah) / 0.2f;
                int nterm = 4;
                float tid5 = as[5];
                int first = -1;
                for (int j2 = 0; j2 < M2; ++j2) {
                    if (s_a2[j2 * 6 + 5] == tid5) { first = j2; break; }  // first match
                }
                if (first >= 0) {
                    const float* ns = &s_a2[first * 6];
                    float nw0 = ns[2] - ns[0], nh0 = ns[3] - ns[1];
                    float ncx = ns[0] + 0.5f * nw0, ncy = ns[1] + 0.5f * nh0;
                    float nw = fmaxf(nw0, 1.f), nh = fmaxf(nh0, 1.f);
                    t[4] = ((ncx - acx) / aw) / 0.1f;
                    t[5] = ((ncy - acy) / ah) / 0.1f;
                    t[6] = __logf(nw / aw) / 0.2f;
                    t[7] = __logf(nh / ah) / 0.2f;
                    nterm = 8;
                }
                const float* rg = regs + ((size_t)b * A + a) * 8;
                for (int k = 0; k < nterm; ++k) {
                    float d = fabsf(t[k] - rg[k]);
                    sum += (d <= (1.0f / 9.0f)) ? (4.5f * d * d) : (d - (0.5f / 9.0f));
                }
            }
        }
#pragma unroll
        for (int off = 32; off > 0; off >>= 1) {
            sum += __shfl_down(sum, off);
            cnt += __shfl_down(cnt, off);
        }
        if ((tid & 63) == 0) { s_red[tid >> 6] = sum; s_redi[tid >> 6] = cnt; }
        __syncthreads();
        if (tid == 0) {
            atomicAdd(&reg_sum[b], s_red[0] + s_red[1] + s_red[2] + s_red[3]);
            atomicAdd(&npos[b], s_redi[0] + s_redi[1] + s_redi[2] + s_redi[3]);
        }
    }
}

// ---------------------------------------------------------------------------
// k_final: per-sample normalization + batch mean -> out[0], out[1]
// ---------------------------------------------------------------------------
__global__ void k_final(const float* __restrict__ cls_sum, const float* __restrict__ reg_sum,
                        const int* __restrict__ npos, float* __restrict__ out, int B) {
    if (blockIdx.x == 0 && threadIdx.x == 0) {
        float c = 0.f, r = 0.f;
        for (int b = 0; b < B; ++b) {
            float np_ = (float)npos[b];
            c += cls_sum[b] / fmaxf(np_, 1.f);
            r += reg_sum[b] / fmaxf(np_ * 8.f, 1.f);
        }
        out[0] = c / (float)B;
        out[1] = r / (float)B;
    }
}

extern "C" void kernel_launch(void* const* d_in, const int* in_sizes, int n_in,
                              void* d_out, int out_size, void* d_ws, size_t ws_size,
                              hipStream_t stream) {
    const float* cls = (const float*)d_in[0];
    const float* regs = (const float*)d_in[1];
    const float* anchors = (const float*)d_in[2];
    const float* ann1 = (const float*)d_in[3];
    const float* ann2 = (const float*)d_in[4];
    float* out = (float*)d_out;

    const int A = in_sizes[2] / 4;           // anchors [1,A,4]
    const int B = in_sizes[1] / (A * 8);     // regressions [B,A,8]
    const int C = in_sizes[0] / (B * A);     // classifications [B,A,C]
    const int M = in_sizes[3] / (B * 6);     // annotations1 [B,M,6]
    const int M2 = in_sizes[4] / (B * 6);    // annotations2 [B,M2,6]

    char* ws = (char*)d_ws;
    size_t off = 0;
    ull* bpi = (ull*)(ws + off);      off += (size_t)B * M * sizeof(ull);   off = (off + 255) & ~(size_t)255;
    int* npos = (int*)(ws + off);     off += (size_t)B * sizeof(int);       off = (off + 255) & ~(size_t)255;
    float* cls_sum = (float*)(ws + off); off += (size_t)B * sizeof(float);  off = (off + 255) & ~(size_t)255;
    float* reg_sum = (float*)(ws + off); off += (size_t)B * sizeof(float);  off = (off + 255) & ~(size_t)255;
    float* bto = (float*)(ws + off);  off += (size_t)B * A * sizeof(float); off = (off + 255) & ~(size_t)255;
    int* bti = (int*)(ws + off);      off += (size_t)B * A * sizeof(int);

    int initN = (B * M > B) ? B * M : B;
    k_init<<<dim3((initN + 255) / 256), dim3(256), 0, stream>>>(bpi, npos, cls_sum, reg_sum, B * M, B);

    dim3 g1((A + 1023) / 1024, B);
    k_iou<<<g1, dim3(256), 0, stream>>>(anchors, ann1, bto, bti, bpi, A, M);

    k_force<<<dim3(1), dim3(M, B), 0, stream>>>(bpi, bto, bti, A, M, B);

    const int NBC = (A + CTILE - 1) / CTILE;   // cls tiles per b
    const int NBR = (A + 255) / 256;           // reg blocks per b
    dim3 g2(B * (NBC + NBR));
    if (C % 4 == 0 && C / 4 == 20)
        k_cr<20><<<g2, dim3(256), 0, stream>>>(cls, regs, anchors, ann1, ann2, bto, bti,
                                               cls_sum, reg_sum, npos,
                                               A, C / 4, M, M2, B, NBC, NBR);
    else
        k_cr<0><<<g2, dim3(256), 0, stream>>>(cls, regs, anchors, ann1, ann2, bto, bti,
                                              cls_sum, reg_sum, npos,
                                              A, C / 4, M, M2, B, NBC, NBR);

    k_final<<<1, 1, 0, stream>>>(cls_sum, reg_sum, npos, out, B);
}